// Round 5
// baseline (118.103 us; speedup 1.0000x reference)
//
#include <hip/hip_runtime.h>

typedef unsigned short u16t;
typedef unsigned int u32t;
typedef __bf16 bf16x8 __attribute__((ext_vector_type(8)));
typedef float f32x4 __attribute__((ext_vector_type(4)));
typedef float f32x16 __attribute__((ext_vector_type(16)));
typedef unsigned int u32x4 __attribute__((ext_vector_type(4)));
typedef unsigned int u32x2 __attribute__((ext_vector_type(2)));

#define DEV static __device__ __forceinline__

DEV u16t f2bf(float f){
  u32t u = __builtin_bit_cast(u32t, f);
  u += 0x7fffu + ((u >> 16) & 1u);   // RNE
  return (u16t)(u >> 16);
}

DEV u32t cvtpk(float lo, float hi){
  u32t r;
  asm("v_cvt_pk_bf16_f32 %0, %1, %2" : "=v"(r) : "v"(lo), "v"(hi));
  return r;
}

// v_permlane32_swap_b32: a.hi32lanes <-> b.lo32lanes
DEV void plswap(u32t &a, u32t &b){
  asm("v_permlane32_swap_b32 %0, %1" : "+v"(a), "+v"(b));
}

DEV float fexp2(float x){
#if __has_builtin(__builtin_amdgcn_exp2f)
  return __builtin_amdgcn_exp2f(x);
#else
  return exp2f(x);
#endif
}

DEV void gll16(const void* g, void* l){
  __builtin_amdgcn_global_load_lds((const __attribute__((address_space(1))) void*)g,
                                   (__attribute__((address_space(3))) void*)l, 16, 0, 0);
}

DEV f32x4 mfma16(bf16x8 a, bf16x8 b, f32x4 c){
  return __builtin_amdgcn_mfma_f32_16x16x32_bf16(a, b, c, 0, 0, 0);
}

DEV f32x16 mfma32(bf16x8 a, bf16x8 b, f32x16 c){
  return __builtin_amdgcn_mfma_f32_32x32x16_bf16(a, b, c, 0, 0, 0);
}

// ---------------- cast x: fp32 -> bf16 ----------------
__global__ __launch_bounds__(256) void k_cast_x(const float4* __restrict__ x, u16t* __restrict__ xb){
  int idx = blockIdx.x * 256 + threadIdx.x;
  float4 v = x[idx];
  ushort4 o = make_ushort4(f2bf(v.x), f2bf(v.y), f2bf(v.z), f2bf(v.w));
  *(ushort4*)&xb[idx * 4] = o;
}

// ---------------- cast weights; fold 0.125*log2(e) into Wq ----------------
__global__ __launch_bounds__(256) void k_cast_w(const float* __restrict__ Wq, const float* __restrict__ Wk,
                         const float* __restrict__ Wv, const float* __restrict__ Wp,
                         u16t* __restrict__ wqkv, u16t* __restrict__ wp){
  int idx = blockIdx.x * 256 + threadIdx.x;  // 0..262143
  if (idx < 196608){
    float v;
    if (idx < 65536)        v = Wq[idx] * 0.1803368801f;   // 0.125 * log2(e)
    else if (idx < 131072)  v = Wk[idx - 65536];
    else                    v = Wv[idx - 131072];
    wqkv[idx] = f2bf(v);
  } else {
    int j = idx - 196608;
    wp[j] = f2bf(Wp[j]);
  }
}

// ---------------- bf16 GEMM: out[m,n] = sum_k A[m,k]*W[n,k] ----------------
// BM=128, BN=64, BK=64, 4 waves (2x2). LDS 16B-chunk XOR swizzle.
// QKV epilogue: Q,K -> [bh][n][64]; V -> tile-blocked pre-swizzled [bh][nt][64 d][64].
template<bool IS_QKV>
__global__ __launch_bounds__(256) void k_gemm(const u16t* __restrict__ A, const u16t* __restrict__ W,
    const float* __restrict__ bias, u16t* __restrict__ oq, u16t* __restrict__ okk, u16t* __restrict__ vtg,
    float* __restrict__ op, int Ntot){
  __shared__ u32x4 sm[1536];
  const int tid = threadIdx.x, lane = tid & 63, w = tid >> 6, g = lane >> 4, li = lane & 15;
  const int m0 = blockIdx.x * 128, n0 = blockIdx.y * 64;
  const int wm = w >> 1, wn = w & 1;
  f32x4 acc[4][2] = {};
  for (int kk = 0; kk < 4; ++kk){
    #pragma unroll
    for (int rnd = 0; rnd < 4; ++rnd){
      int cid = rnd * 256 + tid;
      int row = cid >> 3, ch = cid & 7;
      const u16t* src = A + (m0 + row) * 256 + kk * 64 + ((ch ^ (row & 7)) << 3);
      gll16(src, (char*)sm + (rnd * 256 + w * 64) * 16);
    }
    #pragma unroll
    for (int rnd = 0; rnd < 2; ++rnd){
      int cid = rnd * 256 + tid;
      int row = cid >> 3, ch = cid & 7;
      const u16t* src = W + (n0 + row) * 256 + kk * 64 + ((ch ^ (row & 7)) << 3);
      gll16(src, (char*)sm + 16384 + (rnd * 256 + w * 64) * 16);
    }
    __syncthreads();
    #pragma unroll
    for (int ks = 0; ks < 2; ++ks){
      bf16x8 bfr[2];
      #pragma unroll
      for (int nj = 0; nj < 2; ++nj){
        int row = wn * 32 + nj * 16 + li;
        bfr[nj] = __builtin_bit_cast(bf16x8, sm[1024 + row * 8 + ((ks * 4 + g) ^ (row & 7))]);
      }
      #pragma unroll
      for (int mi = 0; mi < 4; ++mi){
        int row = wm * 64 + mi * 16 + li;
        bf16x8 af = __builtin_bit_cast(bf16x8, sm[row * 8 + ((ks * 4 + g) ^ (row & 7))]);
        #pragma unroll
        for (int nj = 0; nj < 2; ++nj)
          acc[mi][nj] = mfma16(af, bfr[nj], acc[mi][nj]);
      }
    }
    __syncthreads();
  }
  if (IS_QKV){
    const int which = n0 >> 8, h = (n0 >> 6) & 3;
    if (which == 2){
      // V^T via LDS bounce, then store tile-blocked pre-swizzled: [bh][nt][d][ (c^(d&7))*8 .. ]
      u16t* smv = (u16t*)sm;
      #pragma unroll
      for (int mi = 0; mi < 4; ++mi){
        #pragma unroll
        for (int nj = 0; nj < 2; ++nj){
          int d = wn * 32 + nj * 16 + li;
          int mloc = wm * 64 + mi * 16 + g * 4;
          u32x2 pk2;
          pk2.x = cvtpk(acc[mi][nj][0], acc[mi][nj][1]);
          pk2.y = cvtpk(acc[mi][nj][2], acc[mi][nj][3]);
          int chk = mloc >> 3, inner = (mloc & 7) * 2;
          *(u32x2*)((char*)smv + d * 256 + (((chk ^ (d & 7))) << 4) + inner) = pk2;
        }
      }
      __syncthreads();
      const int b = m0 >> 12, bh2 = b * 4 + h, mbase = m0 & 4095;
      #pragma unroll
      for (int rnd = 0; rnd < 4; ++rnd){
        int qq = rnd * 256 + tid;       // 0..1023
        int d = qq >> 4, ch = qq & 15;
        u32x4 val = *(const u32x4*)((char*)smv + d * 256 + ((ch ^ (d & 7)) << 4));
        int nt = (mbase >> 6) + (ch >> 3);
        int cs = (ch & 7) ^ (d & 7);
        *(u32x4*)&vtg[((size_t)(bh2 * 64 + nt) * 64 + d) * 64 + cs * 8] = val;
      }
    } else {
      u16t* outp = which == 0 ? oq : okk;
      #pragma unroll
      for (int mi = 0; mi < 4; ++mi){
        int m = m0 + wm * 64 + mi * 16 + g * 4;
        int b = m >> 12, nn = m & 4095;
        #pragma unroll
        for (int nj = 0; nj < 2; ++nj){
          int d = wn * 32 + nj * 16 + li;
          #pragma unroll
          for (int r = 0; r < 4; ++r)
            outp[((b * 4 + h) * 4096 + nn + r) * 64 + d] = f2bf(acc[mi][nj][r]);
        }
      }
    }
  } else {
    #pragma unroll
    for (int mi = 0; mi < 4; ++mi){
      int m = m0 + wm * 64 + mi * 16 + g * 4;
      #pragma unroll
      for (int nj = 0; nj < 2; ++nj){
        int n = n0 + wn * 32 + nj * 16 + li;
        float bv = bias[n];
        #pragma unroll
        for (int r = 0; r < 4; ++r)
          op[(m + r) * Ntot + n] = acc[mi][nj][r] + bv;
      }
    }
  }
}

// ---------------- flash attention: K in registers, V in LDS, phase-reordered ----------------
// 1024 blocks = 16 bh x 64 q-tiles(64 rows); 2 waves share q-rows, disjoint KV halves.
// Iter t: [A exp/pack S(t)] [vmcnt(8)] [E PV(t)] [B QK(t+1)] [C stage V(t+1), load K(t+2)].
__global__ __launch_bounds__(128, 2) void k_flash(const u16t* __restrict__ q,
    const u16t* __restrict__ kg, const u16t* __restrict__ vt, u16t* __restrict__ ao){
  __shared__ char sm[33280];   // wave w: 2 x 8KB V bufs at w*16384; lsums @32768
  const int tid = threadIdx.x, lane = tid & 63, w = tid >> 6;
  const int hi = lane >> 5, p = lane & 31;
  const int bid = blockIdx.x;
  const int swz = (bid & 7) * 128 + (bid >> 3);   // XCD-aware, bijective (1024%8==0)
  const int bh = swz >> 6, qt = swz & 63;
  const int rowbase = qt * 64;

  const char* kp0 = (const char*)(kg + (size_t)bh * 262144 + (size_t)w * 131072) + p * 128 + hi * 16;
  const char* kp1 = kp0 + 4096;                    // rows 32..63 of the tile
  const char* vp0 = (const char*)vt + (size_t)bh * 524288 + (size_t)w * 262144 + (size_t)lane * 16;
  const char* vp1 = vp0 + 4096;
  char* Vb0 = sm + w * 16384;
  char* Vb1 = Vb0 + 8192;

  // Q B-frags: qf[it][kk]: lane holds Q[rowbase+it*32+p][k=kk*16+8hi+e]
  u32x4 qf[2][4];
  #pragma unroll
  for (int it = 0; it < 2; ++it)
    #pragma unroll
    for (int kk = 0; kk < 4; ++kk)
      qf[it][kk] = *(const u32x4*)&q[((size_t)bh * 4096 + rowbase + it * 32 + p) * 64 + kk * 16 + hi * 8];

  f32x16 ot[2][2] = {};      // [it][dt]
  float lsp[2][4] = {};      // per-lane lsum partials
  u32x4 kreg[2][4];          // [jt][kk] A-frags of K tile
  f32x16 st[2][2];
  const f32x16 fz = {};

  // ---- prologue: K(0) -> regs, V(0) -> LDS buf0, QK(0), K(1) -> regs ----
  #pragma unroll
  for (int jt = 0; jt < 2; ++jt)
    #pragma unroll
    for (int kk = 0; kk < 4; ++kk)
      kreg[jt][kk] = *(const u32x4*)((jt ? kp1 : kp0) + kk * 32);
  kp0 += 8192; kp1 += 8192;
  #pragma unroll
  for (int i = 0; i < 8; ++i)
    gll16((i < 4 ? vp0 : vp1) + (i & 3) * 1024, Vb0 + i * 1024 + lane * 16);
  vp0 += 8192; vp1 += 8192;
  #pragma unroll
  for (int jt = 0; jt < 2; ++jt)
    #pragma unroll
    for (int it = 0; it < 2; ++it){
      f32x16 a = mfma32(__builtin_bit_cast(bf16x8, kreg[jt][0]), __builtin_bit_cast(bf16x8, qf[it][0]), fz);
      a = mfma32(__builtin_bit_cast(bf16x8, kreg[jt][1]), __builtin_bit_cast(bf16x8, qf[it][1]), a);
      a = mfma32(__builtin_bit_cast(bf16x8, kreg[jt][2]), __builtin_bit_cast(bf16x8, qf[it][2]), a);
      a = mfma32(__builtin_bit_cast(bf16x8, kreg[jt][3]), __builtin_bit_cast(bf16x8, qf[it][3]), a);
      st[it][jt] = a;
    }
  #pragma unroll
  for (int jt = 0; jt < 2; ++jt)
    #pragma unroll
    for (int kk = 0; kk < 4; ++kk)
      kreg[jt][kk] = *(const u32x4*)((jt ? kp1 : kp0) + kk * 32);
  kp0 += 8192; kp1 += 8192;

  #pragma unroll 1
  for (int t = 0; t < 32; ++t){
    // ---- A: exp2 + lsum + pack S(t) -> pf ----
    u32x4 pf[2][2][2];       // [it][jt][s]
    #pragma unroll
    for (int it = 0; it < 2; ++it)
      #pragma unroll
      for (int jt = 0; jt < 2; ++jt){
        float e[16];
        #pragma unroll
        for (int r = 0; r < 16; ++r)
          e[r] = fexp2(st[it][jt][r]);
        #pragma unroll
        for (int r = 0; r < 16; ++r)
          lsp[it][r & 3] += e[r];
        #pragma unroll
        for (int s = 0; s < 2; ++s){
          u32t a0 = cvtpk(e[s*8+0], e[s*8+1]);
          u32t a1 = cvtpk(e[s*8+2], e[s*8+3]);
          u32t b0 = cvtpk(e[s*8+4], e[s*8+5]);
          u32t b1 = cvtpk(e[s*8+6], e[s*8+7]);
          plswap(a0, b0);
          plswap(a1, b1);
          pf[it][jt][s] = (u32x4){a0, a1, b0, b1};
        }
      }
    // ---- V(t) landed ----
    asm volatile("s_waitcnt vmcnt(8)" ::: "memory");
    const char* vbcur = (t & 1) ? Vb1 : Vb0;
    __builtin_amdgcn_s_setprio(1);
    // ---- E: PV(t) ----
    #pragma unroll
    for (int jt = 0; jt < 2; ++jt)
      #pragma unroll
      for (int s = 0; s < 2; ++s)
        #pragma unroll
        for (int dt = 0; dt < 2; ++dt){
          int row = dt * 32 + p;
          bf16x8 vf = __builtin_bit_cast(bf16x8,
              *(const u32x4*)(vbcur + row * 128 + ((((jt * 2 + s) * 2 + hi) ^ (row & 7)) << 4)));
          ot[0][dt] = mfma32(vf, __builtin_bit_cast(bf16x8, pf[0][jt][s]), ot[0][dt]);
          ot[1][dt] = mfma32(vf, __builtin_bit_cast(bf16x8, pf[1][jt][s]), ot[1][dt]);
        }
    // ---- B: QK(t+1) ----
    #pragma unroll
    for (int jt = 0; jt < 2; ++jt)
      #pragma unroll
      for (int it = 0; it < 2; ++it){
        f32x16 a = mfma32(__builtin_bit_cast(bf16x8, kreg[jt][0]), __builtin_bit_cast(bf16x8, qf[it][0]), fz);
        a = mfma32(__builtin_bit_cast(bf16x8, kreg[jt][1]), __builtin_bit_cast(bf16x8, qf[it][1]), a);
        a = mfma32(__builtin_bit_cast(bf16x8, kreg[jt][2]), __builtin_bit_cast(bf16x8, qf[it][2]), a);
        a = mfma32(__builtin_bit_cast(bf16x8, kreg[jt][3]), __builtin_bit_cast(bf16x8, qf[it][3]), a);
        st[it][jt] = a;
      }
    __builtin_amdgcn_s_setprio(0);
    // ---- C: stage V(t+1), load K(t+2) ----
    char* vbn = (t & 1) ? Vb0 : Vb1;
    #pragma unroll
    for (int i = 0; i < 8; ++i)
      gll16((i < 4 ? vp0 : vp1) + (i & 3) * 1024, vbn + i * 1024 + lane * 16);
    vp0 += 8192; vp1 += 8192;
    #pragma unroll
    for (int jt = 0; jt < 2; ++jt)
      #pragma unroll
      for (int kk = 0; kk < 4; ++kk)
        kreg[jt][kk] = *(const u32x4*)((jt ? kp1 : kp0) + kk * 32);
    kp0 += 8192; kp1 += 8192;
  }
  asm volatile("s_waitcnt vmcnt(0)" ::: "memory");   // drain tail stages before LDS reuse

  // lsum per wave: lane p holds l[it] for row it*32+p
  float l4[2];
  #pragma unroll
  for (int it = 0; it < 2; ++it){
    float v = (lsp[it][0] + lsp[it][1]) + (lsp[it][2] + lsp[it][3]);
    v += __shfl_xor(v, 32);
    l4[it] = v;
  }
  __syncthreads();   // both waves done with V buffers

  // write O-partials as [it][q 32][d 64] f32 into own 16KB region (quad-XOR swizzle)
  char* reg = sm + w * 16384;
  #pragma unroll
  for (int it = 0; it < 2; ++it)
    #pragma unroll
    for (int dt = 0; dt < 2; ++dt)
      #pragma unroll
      for (int s = 0; s < 4; ++s){
        f32x4 v4 = {ot[it][dt][4*s+0], ot[it][dt][4*s+1], ot[it][dt][4*s+2], ot[it][dt][4*s+3]};
        int quad = 2 * s + hi + 8 * dt;              // d0/4, d0 = 8s+4hi+32dt
        *(f32x4*)(reg + it * 8192 + p * 256 + ((quad ^ (p & 15)) << 4)) = v4;
      }
  // lsums exchange: [wave][it][q]
  float* lsums = (float*)(sm + 32768);
  if (lane < 32){
    lsums[(w * 2 + 0) * 32 + lane] = l4[0];
    lsums[(w * 2 + 1) * 32 + lane] = l4[1];
  }
  __syncthreads();

  // merge: wave w finalizes rows it=w: O = P0 + P1, * 1/(l0+l1); store row-major
  {
    const int qloc = lane >> 1, dh = lane & 1;       // q in [0,32), d-half
    float ltot = lsums[(0 * 2 + w) * 32 + qloc] + lsums[(1 * 2 + w) * 32 + qloc];
    float inv = __builtin_amdgcn_rcpf(ltot);
    const int b = bh >> 2, h = bh & 3;
    u16t* dst = ao + ((size_t)b * 4096 + rowbase + w * 32 + qloc) * 256 + h * 64 + dh * 32;
    u32t pk[16];
    #pragma unroll
    for (int k = 0; k < 8; ++k){
      int quad = dh * 8 + k;
      f32x4 a = *(const f32x4*)(sm + 0 * 16384 + w * 8192 + qloc * 256 + ((quad ^ (qloc & 15)) << 4));
      f32x4 c = *(const f32x4*)(sm + 1 * 16384 + w * 8192 + qloc * 256 + ((quad ^ (qloc & 15)) << 4));
      f32x4 o = (a + c) * inv;
      pk[2*k]   = cvtpk(o[0], o[1]);
      pk[2*k+1] = cvtpk(o[2], o[3]);
    }
    #pragma unroll
    for (int k = 0; k < 4; ++k)
      *(u32x4*)(dst + k * 8) = (u32x4){pk[4*k], pk[4*k+1], pk[4*k+2], pk[4*k+3]};
  }
}

extern "C" void kernel_launch(void* const* d_in, const int* in_sizes, int n_in,
                              void* d_out, int out_size, void* d_ws, size_t ws_size,
                              hipStream_t stream){
  (void)in_sizes; (void)n_in; (void)out_size; (void)ws_size;
  const float* x  = (const float*)d_in[0];
  const float* Wq = (const float*)d_in[1];
  const float* Wk = (const float*)d_in[2];
  const float* Wv = (const float*)d_in[3];
  const float* Wp = (const float*)d_in[4];
  const float* bp = (const float*)d_in[5];
  float* out = (float*)d_out;

  u16t* ws   = (u16t*)d_ws;
  u16t* xb   = ws;                       // [16384][256] bf16 x
  u16t* qg   = ws + 4194304;             // [16 bh][4096][64]
  u16t* kg   = ws + 8388608;             // [16 bh][4096][64]
  u16t* vtg  = ws + 12582912;            // [16 bh][64 nt][64 d][64] tile-blocked V^T (pre-swizzled)
  u16t* ao   = ws + 16777216;            // [16384][256] attn out bf16
  u16t* wqkv = ws + 20971520;            // [768][256]
  u16t* wpb  = ws + 21168128;            // [256][256]

  k_cast_x<<<4096, 256, 0, stream>>>((const float4*)x, xb);
  k_cast_w<<<1024, 256, 0, stream>>>(Wq, Wk, Wv, Wp, wqkv, wpb);
  k_gemm<true><<<dim3(128, 12), 256, 0, stream>>>(xb, wqkv, nullptr, qg, kg, vtg, nullptr, 768);
  k_flash<<<1024, 128, 0, stream>>>(qg, kg, vtg, ao);
  k_gemm<false><<<dim3(128, 4), 256, 0, stream>>>(ao, wpb, bp, nullptr, nullptr, nullptr, out, 256);
}